// Round 1
// baseline (227.605 us; speedup 1.0000x reference)
//
#include <hip/hip_runtime.h>
#include <stdint.h>
#include <stddef.h>

// ---------------------------------------------------------------------------
// Fused transformer attention block for MI355X (gfx950)
//   x[2,2048,1024] fp32 -> QKV proj -> RoPE -> 16-head softmax attn -> out proj
// Strategy: bf16 MFMA (16x16x32) everywhere, fp32 accumulate.
// ---------------------------------------------------------------------------

typedef short          bf16x8 __attribute__((ext_vector_type(8)));
typedef float          f32x4  __attribute__((ext_vector_type(4)));
typedef unsigned short u16x4  __attribute__((ext_vector_type(4)));
typedef unsigned short u16x8  __attribute__((ext_vector_type(8)));

#define B_   2
#define L_   2048
#define D_   1024
#define H_   16
#define HD_  64
#define BL_  4096           // B_*L_
#define LOG2E 1.4426950408889634f

__device__ __forceinline__ unsigned short f2bf(float f) {   // RNE f32->bf16
  unsigned int u = __float_as_uint(f);
  u += 0x7FFFu + ((u >> 16) & 1u);
  return (unsigned short)(u >> 16);
}
__device__ __forceinline__ float bf2f(unsigned short h) {
  return __uint_as_float(((unsigned int)h) << 16);
}

// async global->LDS, 16B per lane; lds dest must be wave-uniform (guide m104)
__device__ __forceinline__ void gload_lds16(const unsigned short* g, unsigned short* l) {
  __builtin_amdgcn_global_load_lds(
      (__attribute__((address_space(1))) void*)g,
      (__attribute__((address_space(3))) void*)l, 16, 0, 0);
}

// ---------------------------------------------------------------------------
// x (fp32) -> bf16, vectorized 8/thread
// ---------------------------------------------------------------------------
__global__ void __launch_bounds__(256)
cast_x(const float* __restrict__ src, u16x8* __restrict__ dst, int n8) {
  const int i = blockIdx.x * 256 + threadIdx.x;
  if (i >= n8) return;
  const float4 a = ((const float4*)src)[2 * i];
  const float4 b = ((const float4*)src)[2 * i + 1];
  u16x8 o;
  o[0] = f2bf(a.x); o[1] = f2bf(a.y); o[2] = f2bf(a.z); o[3] = f2bf(a.w);
  o[4] = f2bf(b.x); o[5] = f2bf(b.y); o[6] = f2bf(b.z); o[7] = f2bf(b.w);
  dst[i] = o;
}

// ---------------------------------------------------------------------------
// W[K][N] fp32 -> Wt[N][K] bf16 (LDS tile transpose, padded)
// ---------------------------------------------------------------------------
__global__ void __launch_bounds__(256)
transpose_cast(const float* __restrict__ src, unsigned short* __restrict__ dst,
               int K, int N) {
  __shared__ float tile[32][33];
  const int n0 = blockIdx.x * 32, k0 = blockIdx.y * 32;
  const int tx = threadIdx.x, ty = threadIdx.y;   // (32,8)
#pragma unroll
  for (int i = 0; i < 4; ++i)
    tile[ty * 4 + i][tx] = src[(size_t)(k0 + ty * 4 + i) * N + n0 + tx];
  __syncthreads();
#pragma unroll
  for (int i = 0; i < 4; ++i)
    dst[(size_t)(n0 + ty * 4 + i) * K + k0 + tx] = f2bf(tile[tx][ty * 4 + i]);
}

// ---------------------------------------------------------------------------
// GEMM (m97 structure): C[M][N] = A[M][K](bf16) * Bt[N][K](bf16)^T + bias
// 128x128 tile, BK=32, 4 waves 2x2, each wave 64x64 = 4x4 16x16 frags.
// MODE 0: scatter epilogue -> Qb/Kb [bh][L][64], Vt [bh][64][L]  (bf16)
// MODE 1: plain epilogue -> outF fp32 [M][N]
// ---------------------------------------------------------------------------
template <int MODE>
__global__ void __launch_bounds__(256)
gemm_bt(const unsigned short* __restrict__ A,
        const unsigned short* __restrict__ Bt,
        const float* __restrict__ bias,
        float* __restrict__ outF,
        unsigned short* __restrict__ Qb,
        unsigned short* __restrict__ Kb,
        unsigned short* __restrict__ Vt,
        int M, int N, int K) {
  __shared__ unsigned short As[2][128 * 32];
  __shared__ unsigned short Bs[2][128 * 32];
  const int tid = threadIdx.x;
  const int w = tid >> 6, l = tid & 63;
  const int lg = l >> 4, ll = l & 15;
  const int m0 = blockIdx.y * 128, n0 = blockIdx.x * 128;
  const int wm = (w >> 1) * 64, wn = (w & 1) * 64;

  f32x4 acc[4][4] = {};

  // staging geometry: byte off = c*4096 + w*1024 + l*16 within 8KB tile
  const int srow = w * 16 + (l >> 2);     // + c*64
  const int scol = (l & 3) * 8;
  const unsigned short* gA = A  + (size_t)(m0 + srow) * K + scol;
  const unsigned short* gB = Bt + (size_t)(n0 + srow) * K + scol;
  const int ldsoff = (w * 1024) >> 1;     // ushort index, + c*2048

  const int NT = K >> 5;
  int buf = 0;

  auto stage = [&](int bsel, int kt) {
    const int kk = kt * 32;
#pragma unroll
    for (int c = 0; c < 2; ++c) {
      gload_lds16(gA + (size_t)c * 64 * K + kk, &As[bsel][ldsoff + c * 2048]);
      gload_lds16(gB + (size_t)c * 64 * K + kk, &Bs[bsel][ldsoff + c * 2048]);
    }
  };

  stage(0, 0);
  for (int kt = 0; kt < NT; ++kt) {
    __syncthreads();                      // drains vmcnt -> staged tile visible
    if (kt + 1 < NT) stage(buf ^ 1, kt + 1);
    const unsigned short* pa = &As[buf][0];
    const unsigned short* pb = &Bs[buf][0];
    bf16x8 af[4], bfv[4];
#pragma unroll
    for (int mi = 0; mi < 4; ++mi)
      af[mi] = *(const bf16x8*)(pa + (wm + mi * 16 + ll) * 32 + 8 * lg);
#pragma unroll
    for (int ni = 0; ni < 4; ++ni)
      bfv[ni] = *(const bf16x8*)(pb + (wn + ni * 16 + ll) * 32 + 8 * lg);
#pragma unroll
    for (int mi = 0; mi < 4; ++mi)
#pragma unroll
      for (int ni = 0; ni < 4; ++ni)
        acc[mi][ni] = __builtin_amdgcn_mfma_f32_16x16x32_bf16(
            af[mi], bfv[ni], acc[mi][ni], 0, 0, 0);
    buf ^= 1;
  }

  // epilogue. C layout: row = (l>>4)*4 + reg, col = l&15   (guide m89/m91)
  if (MODE == 0) {
#pragma unroll
    for (int ni = 0; ni < 4; ++ni) {
      const int n = n0 + wn + ni * 16 + ll;
      const float bv = bias[n];
      const int t = n >> 10;              // 0=q 1=k 2=v (wave-uniform: 16 | 1024)
      const int r = n & 1023;
      const int h = r >> 6, d = r & 63;
#pragma unroll
      for (int mi = 0; mi < 4; ++mi) {
        const int row0 = m0 + wm + mi * 16 + lg * 4;
        const int b   = row0 >> 11;       // / 2048
        const int pos = row0 & 2047;
        const int bh  = b * H_ + h;
        if (t == 2) {                     // V transposed: Vt[bh][d][pos..pos+3]
          u16x4 pk;
#pragma unroll
          for (int rg = 0; rg < 4; ++rg) pk[rg] = f2bf(acc[mi][ni][rg] + bv);
          *(u16x4*)(Vt + ((size_t)bh * HD_ + d) * L_ + pos) = pk;
        } else {
          unsigned short* dst = (t == 0) ? Qb : Kb;
#pragma unroll
          for (int rg = 0; rg < 4; ++rg)
            dst[((size_t)bh * L_ + pos + rg) * HD_ + d] = f2bf(acc[mi][ni][rg] + bv);
        }
      }
    }
  } else {
#pragma unroll
    for (int ni = 0; ni < 4; ++ni) {
      const int n = n0 + wn + ni * 16 + ll;
      const float bv = bias[n];
#pragma unroll
      for (int mi = 0; mi < 4; ++mi) {
        const int row0 = m0 + wm + mi * 16 + lg * 4;
#pragma unroll
        for (int rg = 0; rg < 4; ++rg)
          outF[(size_t)(row0 + rg) * N + n] = acc[mi][ni][rg] + bv;
      }
    }
  }
}

// ---------------------------------------------------------------------------
// RoPE in place on Qb,Kb [bh][L][64]; pairs (j, j+32), softmax scale folded
// into Q. angle = pos * 10000^(-j/32).
// ---------------------------------------------------------------------------
__global__ void __launch_bounds__(256)
rope_kernel(unsigned short* __restrict__ Qb, unsigned short* __restrict__ Kb) {
  const int idx = blockIdx.x * 256 + threadIdx.x;   // 2 * 2^21 total
  const int arr = idx >> 21;
  const int r   = idx & 0x1FFFFF;
  const int j   = r & 31;
  const int pos = (r >> 5) & 2047;
  const int bh  = r >> 16;
  unsigned short* p = (arr ? Kb : Qb) + ((size_t)bh * L_ + pos) * HD_;
  const float inv = exp2f(-(float)j * 0.4152410118609203f);  // log2(1e4)/32
  const float ang = (float)pos * inv;
  float s, c;
  sincosf(ang, &s, &c);
  const float q1 = bf2f(p[j]), q2 = bf2f(p[j + 32]);
  const float sc = arr ? 1.0f : 0.125f;                      // hd^-0.5 on Q
  p[j]      = f2bf((q1 * c - q2 * s) * sc);
  p[j + 32] = f2bf((q2 * c + q1 * s) * sc);
}

// ---------------------------------------------------------------------------
// Flash attention: block = 4 waves x 32 q-rows = 128 rows of one (b,h).
// KVBLK=64. K,V read direct from global (per-head K+V=512KB, L2/L3-resident).
// P transposed via per-wave XOR-swizzled LDS (row-stride-128B fix, G4).
// ---------------------------------------------------------------------------
__global__ void __launch_bounds__(256)
attn_kernel(const unsigned short* __restrict__ Qb,
            const unsigned short* __restrict__ Kb,
            const unsigned short* __restrict__ Vt,
            unsigned short* __restrict__ Ob) {
  __shared__ unsigned short Pl[4][2048];     // per-wave 32x64 bf16
  const int tid = threadIdx.x, w = tid >> 6, l = tid & 63;
  const int lg = l >> 4, ll = l & 15;
  const int bid = blockIdx.x;
  const int bh  = bid >> 4;                  // 16 blocks per (b,h)
  const int q0  = (bid & 15) * 128 + w * 32;
  const unsigned short* Qp = Qb + ((size_t)bh * L_ + q0) * HD_;
  const unsigned short* Kp = Kb + (size_t)bh * L_ * HD_;
  const unsigned short* Vp = Vt + (size_t)bh * HD_ * L_;
  unsigned short* Pw = &Pl[w][0];

  // hoist Q fragments (A-operand: row = l&15, k = 8*(l>>4)+j)
  bf16x8 qf[2][2];
#pragma unroll
  for (int mi = 0; mi < 2; ++mi)
#pragma unroll
    for (int ks = 0; ks < 2; ++ks)
      qf[mi][ks] = *(const bf16x8*)(Qp + (size_t)(mi * 16 + ll) * HD_ + ks * 32 + 8 * lg);

  f32x4 o[2][4] = {};
  float mrow[2][4], lrow[2][4];
#pragma unroll
  for (int mi = 0; mi < 2; ++mi)
#pragma unroll
    for (int rg = 0; rg < 4; ++rg) { mrow[mi][rg] = -1e30f; lrow[mi][rg] = 0.f; }

  for (int kv0 = 0; kv0 < L_; kv0 += 64) {
    // ---- S = Q K^T (scale already folded into Q)
    f32x4 s[2][4] = {};
#pragma unroll
    for (int ks = 0; ks < 2; ++ks) {
#pragma unroll
      for (int ni = 0; ni < 4; ++ni) {
        const bf16x8 kf = *(const bf16x8*)(Kp + (size_t)(kv0 + ni * 16 + ll) * HD_ + ks * 32 + 8 * lg);
#pragma unroll
        for (int mi = 0; mi < 2; ++mi)
          s[mi][ni] = __builtin_amdgcn_mfma_f32_16x16x32_bf16(qf[mi][ks], kf, s[mi][ni], 0, 0, 0);
      }
    }
    // ---- online softmax. row r = mi*16 + lg*4 + rg lives on 16 lanes (ll)
#pragma unroll
    for (int mi = 0; mi < 2; ++mi) {
#pragma unroll
      for (int rg = 0; rg < 4; ++rg) {
        float mx = fmaxf(fmaxf(s[mi][0][rg], s[mi][1][rg]),
                         fmaxf(s[mi][2][rg], s[mi][3][rg]));
        mx = fmaxf(mx, __shfl_xor(mx, 1));
        mx = fmaxf(mx, __shfl_xor(mx, 2));
        mx = fmaxf(mx, __shfl_xor(mx, 4));
        mx = fmaxf(mx, __shfl_xor(mx, 8));
        const float mnew = fmaxf(mrow[mi][rg], mx);
        const float f = exp2f((mrow[mi][rg] - mnew) * LOG2E);
        mrow[mi][rg] = mnew;
        lrow[mi][rg] *= f;
#pragma unroll
        for (int ni = 0; ni < 4; ++ni) o[mi][ni][rg] *= f;
        float rs = 0.f;
#pragma unroll
        for (int ni = 0; ni < 4; ++ni) {
          const float p = exp2f((s[mi][ni][rg] - mnew) * LOG2E);
          s[mi][ni][rg] = p;
          rs += p;
        }
        rs += __shfl_xor(rs, 1); rs += __shfl_xor(rs, 2);
        rs += __shfl_xor(rs, 4); rs += __shfl_xor(rs, 8);
        lrow[mi][rg] += rs;
      }
    }
    // ---- P -> LDS (bf16, XOR swizzle byte^=(row&7)<<4)
#pragma unroll
    for (int mi = 0; mi < 2; ++mi)
#pragma unroll
      for (int ni = 0; ni < 4; ++ni)
#pragma unroll
        for (int rg = 0; rg < 4; ++rg) {
          const int row = mi * 16 + lg * 4 + rg;
          const int boff = (row * 128 + (ni * 16 + ll) * 2) ^ ((row & 7) << 4);
          *(unsigned short*)((char*)Pw + boff) = f2bf(s[mi][ni][rg]);
        }
    asm volatile("s_waitcnt lgkmcnt(0)" ::: "memory");
    __builtin_amdgcn_sched_barrier(0);
    // ---- O += P V   (A = P from LDS, B = V from Vt[d][kv], contiguous 16B)
#pragma unroll
    for (int ks = 0; ks < 2; ++ks) {
      bf16x8 pf[2];
#pragma unroll
      for (int mi = 0; mi < 2; ++mi) {
        const int row = mi * 16 + ll;
        const int boff = (row * 128 + ks * 64 + lg * 16) ^ ((row & 7) << 4);
        pf[mi] = *(const bf16x8*)((char*)Pw + boff);
      }
#pragma unroll
      for (int ni = 0; ni < 4; ++ni) {
        const bf16x8 vf = *(const bf16x8*)(Vp + (size_t)(ni * 16 + ll) * L_ + kv0 + ks * 32 + 8 * lg);
#pragma unroll
        for (int mi = 0; mi < 2; ++mi)
          o[mi][ni] = __builtin_amdgcn_mfma_f32_16x16x32_bf16(pf[mi], vf, o[mi][ni], 0, 0, 0);
      }
    }
  }

  // ---- normalize + write Ob[b][l][h*64+d] bf16
  const int b = bh >> 4, h = bh & 15;
  unsigned short* Op = Ob + ((size_t)b * L_ + q0) * D_ + h * HD_;
#pragma unroll
  for (int mi = 0; mi < 2; ++mi)
#pragma unroll
    for (int rg = 0; rg < 4; ++rg) {
      const float inv = 1.0f / lrow[mi][rg];
      const int row = mi * 16 + lg * 4 + rg;
#pragma unroll
      for (int ni = 0; ni < 4; ++ni)
        Op[(size_t)row * D_ + ni * 16 + ll] = f2bf(o[mi][ni][rg] * inv);
    }
}

// ---------------------------------------------------------------------------
extern "C" void kernel_launch(void* const* d_in, const int* in_sizes, int n_in,
                              void* d_out, int out_size, void* d_ws, size_t ws_size,
                              hipStream_t stream) {
  const float* x    = (const float*)d_in[0];
  const float* Wqkv = (const float*)d_in[1];
  const float* bqkv = (const float*)d_in[2];
  const float* Wout = (const float*)d_in[3];
  const float* bout = (const float*)d_in[4];
  float* out = (float*)d_out;

  char* ws = (char*)d_ws;                       // 48 MiB used
  unsigned short* xb    = (unsigned short*)(ws);                    // 8 MiB
  unsigned short* WqkvT = (unsigned short*)(ws + (8ull  << 20));    // 6 MiB
  unsigned short* WoutT = (unsigned short*)(ws + (14ull << 20));    // 2 MiB
  unsigned short* Qb    = (unsigned short*)(ws + (16ull << 20));    // 8 MiB
  unsigned short* Kb    = (unsigned short*)(ws + (24ull << 20));    // 8 MiB
  unsigned short* Vt    = (unsigned short*)(ws + (32ull << 20));    // 8 MiB
  unsigned short* Ob    = (unsigned short*)(ws + (40ull << 20));    // 8 MiB

  cast_x<<<(BL_ * D_ / 8 + 255) / 256, 256, 0, stream>>>(x, (u16x8*)xb, BL_ * D_ / 8);
  transpose_cast<<<dim3(3 * D_ / 32, D_ / 32), dim3(32, 8), 0, stream>>>(Wqkv, WqkvT, D_, 3 * D_);
  transpose_cast<<<dim3(D_ / 32, D_ / 32), dim3(32, 8), 0, stream>>>(Wout, WoutT, D_, D_);

  gemm_bt<0><<<dim3(3 * D_ / 128, BL_ / 128), 256, 0, stream>>>(
      xb, WqkvT, bqkv, nullptr, Qb, Kb, Vt, BL_, 3 * D_, D_);

  rope_kernel<<<(2 * 2097152) / 256, 256, 0, stream>>>(Qb, Kb);

  attn_kernel<<<B_ * H_ * (L_ / 128), 256, 0, stream>>>(Qb, Kb, Vt, Ob);

  gemm_bt<1><<<dim3(D_ / 128, BL_ / 128), 256, 0, stream>>>(
      Ob, WoutT, bout, out, nullptr, nullptr, nullptr, BL_, D_, D_);
}

// Round 2
// 210.545 us; speedup vs baseline: 1.0810x; 1.0810x over previous
//
#include <hip/hip_runtime.h>
#include <stdint.h>
#include <stddef.h>

// ---------------------------------------------------------------------------
// Fused transformer attention block for MI355X (gfx950)
//   x[2,2048,1024] fp32 -> QKV proj(+RoPE fused) -> 16-head softmax attn -> out proj
// bf16 MFMA (16x16x32), fp32 accumulate.
// R2: swapped QK^T (S^T lane-local softmax), defer-max (T13), cvt_pk (T12),
//     LOG2E folded into Q scale, RoPE fused into GEMM1 epilogue.
// ---------------------------------------------------------------------------

typedef short          bf16x8 __attribute__((ext_vector_type(8)));
typedef float          f32x4  __attribute__((ext_vector_type(4)));
typedef unsigned short u16x4  __attribute__((ext_vector_type(4)));
typedef unsigned short u16x8  __attribute__((ext_vector_type(8)));

#define B_   2
#define L_   2048
#define D_   1024
#define H_   16
#define HD_  64
#define BL_  4096           // B_*L_
#define LOG2E 1.4426950408889634f
#define QSC  0.18033688011112042f   // 0.125 * LOG2E (scale+log2e folded into Q)

__device__ __forceinline__ unsigned short f2bf(float f) {   // RNE f32->bf16
  unsigned int u = __float_as_uint(f);
  u += 0x7FFFu + ((u >> 16) & 1u);
  return (unsigned short)(u >> 16);
}
__device__ __forceinline__ float bf2f(unsigned short h) {
  return __uint_as_float(((unsigned int)h) << 16);
}
__device__ __forceinline__ uint32_t cvtpk_bf16(float lo, float hi) {
  uint32_t r;
  asm("v_cvt_pk_bf16_f32 %0, %1, %2" : "=v"(r) : "v"(lo), "v"(hi));
  return r;
}

// async global->LDS, 16B per lane; lds dest must be wave-uniform (guide m104)
__device__ __forceinline__ void gload_lds16(const unsigned short* g, unsigned short* l) {
  __builtin_amdgcn_global_load_lds(
      (__attribute__((address_space(1))) void*)g,
      (__attribute__((address_space(3))) void*)l, 16, 0, 0);
}

// ---------------------------------------------------------------------------
// x (fp32) -> bf16, vectorized 8/thread
// ---------------------------------------------------------------------------
__global__ void __launch_bounds__(256)
cast_x(const float* __restrict__ src, u16x8* __restrict__ dst, int n8) {
  const int i = blockIdx.x * 256 + threadIdx.x;
  if (i >= n8) return;
  const float4 a = ((const float4*)src)[2 * i];
  const float4 b = ((const float4*)src)[2 * i + 1];
  u16x8 o;
  o[0] = f2bf(a.x); o[1] = f2bf(a.y); o[2] = f2bf(a.z); o[3] = f2bf(a.w);
  o[4] = f2bf(b.x); o[5] = f2bf(b.y); o[6] = f2bf(b.z); o[7] = f2bf(b.w);
  dst[i] = o;
}

// ---------------------------------------------------------------------------
// W[K][N] fp32 -> Wt[N][K] bf16 (LDS tile transpose, padded)
// ---------------------------------------------------------------------------
__global__ void __launch_bounds__(256)
transpose_cast(const float* __restrict__ src, unsigned short* __restrict__ dst,
               int K, int N) {
  __shared__ float tile[32][33];
  const int n0 = blockIdx.x * 32, k0 = blockIdx.y * 32;
  const int tx = threadIdx.x, ty = threadIdx.y;   // (32,8)
#pragma unroll
  for (int i = 0; i < 4; ++i)
    tile[ty * 4 + i][tx] = src[(size_t)(k0 + ty * 4 + i) * N + n0 + tx];
  __syncthreads();
#pragma unroll
  for (int i = 0; i < 4; ++i)
    dst[(size_t)(n0 + ty * 4 + i) * K + k0 + tx] = f2bf(tile[tx][ty * 4 + i]);
}

// ---------------------------------------------------------------------------
// GEMM (m97 structure): C[M][N] = A[M][K](bf16) * Bt[N][K](bf16)^T + bias
// 128x128 tile, BK=32, 4 waves 2x2, each wave 64x64 = 4x4 16x16 frags.
// MODE 0: epilogue -> RoPE(Q,K) scatter to Qb/Kb [bh][L][64], V -> Vt [bh][64][L]
//         Q additionally scaled by 0.125*LOG2E.
// MODE 1: plain epilogue -> outF fp32 [M][N]
// ---------------------------------------------------------------------------
template <int MODE>
__global__ void __launch_bounds__(256)
gemm_bt(const unsigned short* __restrict__ A,
        const unsigned short* __restrict__ Bt,
        const float* __restrict__ bias,
        float* __restrict__ outF,
        unsigned short* __restrict__ Qb,
        unsigned short* __restrict__ Kb,
        unsigned short* __restrict__ Vt,
        int M, int N, int K) {
  __shared__ unsigned short As[2][128 * 32];
  __shared__ unsigned short Bs[2][128 * 32];
  const int tid = threadIdx.x;
  const int w = tid >> 6, l = tid & 63;
  const int lg = l >> 4, ll = l & 15;
  const int m0 = blockIdx.y * 128, n0 = blockIdx.x * 128;
  const int wm = (w >> 1) * 64, wn = (w & 1) * 64;

  f32x4 acc[4][4] = {};

  // staging geometry: byte off = c*4096 + w*1024 + l*16 within 8KB tile
  const int srow = w * 16 + (l >> 2);     // + c*64
  const int scol = (l & 3) * 8;
  const unsigned short* gA = A  + (size_t)(m0 + srow) * K + scol;
  const unsigned short* gB = Bt + (size_t)(n0 + srow) * K + scol;
  const int ldsoff = (w * 1024) >> 1;     // ushort index, + c*2048

  const int NT = K >> 5;
  int buf = 0;

  auto stage = [&](int bsel, int kt) {
    const int kk = kt * 32;
#pragma unroll
    for (int c = 0; c < 2; ++c) {
      gload_lds16(gA + (size_t)c * 64 * K + kk, &As[bsel][ldsoff + c * 2048]);
      gload_lds16(gB + (size_t)c * 64 * K + kk, &Bs[bsel][ldsoff + c * 2048]);
    }
  };

  stage(0, 0);
  for (int kt = 0; kt < NT; ++kt) {
    __syncthreads();                      // drains vmcnt -> staged tile visible
    if (kt + 1 < NT) stage(buf ^ 1, kt + 1);
    const unsigned short* pa = &As[buf][0];
    const unsigned short* pb = &Bs[buf][0];
    bf16x8 af[4], bfv[4];
#pragma unroll
    for (int mi = 0; mi < 4; ++mi)
      af[mi] = *(const bf16x8*)(pa + (wm + mi * 16 + ll) * 32 + 8 * lg);
#pragma unroll
    for (int ni = 0; ni < 4; ++ni)
      bfv[ni] = *(const bf16x8*)(pb + (wn + ni * 16 + ll) * 32 + 8 * lg);
#pragma unroll
    for (int mi = 0; mi < 4; ++mi)
#pragma unroll
      for (int ni = 0; ni < 4; ++ni)
        acc[mi][ni] = __builtin_amdgcn_mfma_f32_16x16x32_bf16(
            af[mi], bfv[ni], acc[mi][ni], 0, 0, 0);
    buf ^= 1;
  }

  // epilogue. C layout: row = (l>>4)*4 + reg, col = l&15   (guide m89/m91)
  if (MODE == 0) {
    const int t = (n0 + wn) >> 10;        // 0=q 1=k 2=v, wave-uniform (64 | 1024)
    if (t == 2) {                         // V transposed: Vt[bh][d][pos..pos+3]
#pragma unroll
      for (int ni = 0; ni < 4; ++ni) {
        const int n = n0 + wn + ni * 16 + ll;
        const float bv = bias[n];
        const int r = n & 1023;
        const int h = r >> 6, d = r & 63;
#pragma unroll
        for (int mi = 0; mi < 4; ++mi) {
          const int row0 = m0 + wm + mi * 16 + lg * 4;
          const int b   = row0 >> 11;
          const int pos = row0 & 2047;
          const int bh  = b * H_ + h;
          u16x4 pk;
#pragma unroll
          for (int rg = 0; rg < 4; ++rg) pk[rg] = f2bf(acc[mi][ni][rg] + bv);
          *(u16x4*)(Vt + ((size_t)bh * HD_ + d) * L_ + pos) = pk;
        }
      }
    } else {                              // Q/K: fused RoPE, pairs (d, d+32)
      unsigned short* dst = (t == 0) ? Qb : Kb;
      const float qsc = (t == 0) ? QSC : 1.0f;
      const int h = ((n0 + wn) & 1023) >> 6;   // wave-uniform
#pragma unroll
      for (int ni = 0; ni < 2; ++ni) {
        const int d = ni * 16 + ll;       // 0..31
        const float bv1 = bias[n0 + wn + ni * 16 + ll];
        const float bv2 = bias[n0 + wn + (ni + 2) * 16 + ll];
        const float invf = exp2f(-(float)d * 0.4152410118609203f); // log2(1e4)/32
#pragma unroll
        for (int mi = 0; mi < 4; ++mi) {
          const int row0 = m0 + wm + mi * 16 + lg * 4;
          const int b   = row0 >> 11;
          const int pos0 = row0 & 2047;
          unsigned short* base = dst + (size_t)(b * H_ + h) * L_ * HD_;
#pragma unroll
          for (int rg = 0; rg < 4; ++rg) {
            const int pos = pos0 + rg;
            float sn, cs;
            sincosf((float)pos * invf, &sn, &cs);
            const float q1 = acc[mi][ni][rg] + bv1;
            const float q2 = acc[mi][ni + 2][rg] + bv2;
            base[(size_t)pos * HD_ + d]      = f2bf((q1 * cs - q2 * sn) * qsc);
            base[(size_t)pos * HD_ + d + 32] = f2bf((q2 * cs + q1 * sn) * qsc);
          }
        }
      }
    }
  } else {
#pragma unroll
    for (int ni = 0; ni < 4; ++ni) {
      const int n = n0 + wn + ni * 16 + ll;
      const float bv = bias[n];
#pragma unroll
      for (int mi = 0; mi < 4; ++mi) {
        const int row0 = m0 + wm + mi * 16 + lg * 4;
#pragma unroll
        for (int rg = 0; rg < 4; ++rg)
          outF[(size_t)(row0 + rg) * N + n] = acc[mi][ni][rg] + bv;
      }
    }
  }
}

// ---------------------------------------------------------------------------
// Flash attention, swapped-QK^T structure:
//   block = 4 waves x 32 q-rows; KVBLK=64; K,V direct from global (L2-resident)
//   S^T = mfma(K, Q): lane ll owns q-column, k = ni*16 + lg*4 + rg in-register
//   -> softmax max/sum: in-lane tree + shfl_xor(16/32) only
//   defer-max (T13, thr=8 in log2 domain); P -> LDS via cvt_pk + b64 stores,
//   XOR-swizzled (G4); PV reads P as A-operand (unchanged layout).
// ---------------------------------------------------------------------------
__global__ void __launch_bounds__(256)
attn_kernel(const unsigned short* __restrict__ Qb,
            const unsigned short* __restrict__ Kb,
            const unsigned short* __restrict__ Vt,
            unsigned short* __restrict__ Ob) {
  __shared__ unsigned short Pl[4][2048];     // per-wave 32x64 bf16
  const int tid = threadIdx.x, w = tid >> 6, l = tid & 63;
  const int lg = l >> 4, ll = l & 15;
  const int bid = blockIdx.x;
  const int bh  = bid >> 4;                  // 16 blocks per (b,h)
  const int q0  = (bid & 15) * 128 + w * 32;
  const unsigned short* Qp = Qb + ((size_t)bh * L_ + q0) * HD_;
  const unsigned short* Kp = Kb + (size_t)bh * L_ * HD_;
  const unsigned short* Vp = Vt + (size_t)bh * HD_ * L_;
  unsigned short* Pw = &Pl[w][0];

  // hoist Q fragments (used as B-operand: col = l&15, k = 8*(l>>4)+j)
  bf16x8 qf[2][2];
#pragma unroll
  for (int mi = 0; mi < 2; ++mi)
#pragma unroll
    for (int ks = 0; ks < 2; ++ks)
      qf[mi][ks] = *(const bf16x8*)(Qp + (size_t)(mi * 16 + ll) * HD_ + ks * 32 + 8 * lg);

  f32x4 o[2][4] = {};
  float mrow[2] = {-1e30f, -1e30f};          // log2-domain running max (per q=ll)
  float lrow[2] = {0.f, 0.f};

  for (int kv0 = 0; kv0 < L_; kv0 += 64) {
    // ---- S^T = K Q^T  (scale*log2e already folded into Q)
    f32x4 s[2][4] = {};
#pragma unroll
    for (int ks = 0; ks < 2; ++ks) {
#pragma unroll
      for (int ni = 0; ni < 4; ++ni) {
        const bf16x8 kf = *(const bf16x8*)(Kp + (size_t)(kv0 + ni * 16 + ll) * HD_ + ks * 32 + 8 * lg);
#pragma unroll
        for (int mi = 0; mi < 2; ++mi)
          s[mi][ni] = __builtin_amdgcn_mfma_f32_16x16x32_bf16(kf, qf[mi][ks], s[mi][ni], 0, 0, 0);
      }
    }
    // ---- per-lane max over 16 in-register k-values, then 2 shuffles
    float mx[2];
#pragma unroll
    for (int mi = 0; mi < 2; ++mi) {
      float a0 = fmaxf(fmaxf(s[mi][0][0], s[mi][0][1]), fmaxf(s[mi][0][2], s[mi][0][3]));
      float a1 = fmaxf(fmaxf(s[mi][1][0], s[mi][1][1]), fmaxf(s[mi][1][2], s[mi][1][3]));
      float a2 = fmaxf(fmaxf(s[mi][2][0], s[mi][2][1]), fmaxf(s[mi][2][2], s[mi][2][3]));
      float a3 = fmaxf(fmaxf(s[mi][3][0], s[mi][3][1]), fmaxf(s[mi][3][2], s[mi][3][3]));
      float a  = fmaxf(fmaxf(a0, a1), fmaxf(a2, a3));
      a = fmaxf(a, __shfl_xor(a, 16));
      a = fmaxf(a, __shfl_xor(a, 32));
      mx[mi] = a;
    }
    // ---- defer-max: rescale only when max grew by >8 (log2 domain)
    const bool need = (mx[0] > mrow[0] + 8.f) || (mx[1] > mrow[1] + 8.f);
    if (__any(need)) {
#pragma unroll
      for (int mi = 0; mi < 2; ++mi) {
        const float mnew = fmaxf(mrow[mi], mx[mi]);
        const float f = exp2f(mrow[mi] - mnew);
        mrow[mi] = mnew;
        lrow[mi] *= f;
        float fq[4];
#pragma unroll
        for (int rg = 0; rg < 4; ++rg) fq[rg] = __shfl(f, lg * 4 + rg);
#pragma unroll
        for (int ni = 0; ni < 4; ++ni)
#pragma unroll
          for (int rg = 0; rg < 4; ++rg) o[mi][ni][rg] *= fq[rg];
      }
    }
    // ---- P = exp2(S - m), in-lane sum, pack bf16, b64 store to swizzled LDS
#pragma unroll
    for (int mi = 0; mi < 2; ++mi) {
      float rs = 0.f;
#pragma unroll
      for (int ni = 0; ni < 4; ++ni) {
        const float p0 = exp2f(s[mi][ni][0] - mrow[mi]);
        const float p1 = exp2f(s[mi][ni][1] - mrow[mi]);
        const float p2 = exp2f(s[mi][ni][2] - mrow[mi]);
        const float p3 = exp2f(s[mi][ni][3] - mrow[mi]);
        rs += (p0 + p1) + (p2 + p3);
        uint2 pk;
        pk.x = cvtpk_bf16(p0, p1);
        pk.y = cvtpk_bf16(p2, p3);
        const int boff = (mi * 2048 + ll * 128 + ni * 32 + lg * 8) ^ ((ll & 7) << 4);
        *(uint2*)((char*)Pw + boff) = pk;
      }
      rs += __shfl_xor(rs, 16);
      rs += __shfl_xor(rs, 32);
      lrow[mi] += rs;
    }
    asm volatile("s_waitcnt lgkmcnt(0)" ::: "memory");
    __builtin_amdgcn_sched_barrier(0);
    // ---- O += P V   (A = P from LDS, B = V from Vt[d][kv], contiguous 16B)
#pragma unroll
    for (int ks = 0; ks < 2; ++ks) {
      bf16x8 pf[2];
#pragma unroll
      for (int mi = 0; mi < 2; ++mi) {
        const int row = mi * 16 + ll;
        const int boff = (row * 128 + ks * 64 + lg * 16) ^ ((row & 7) << 4);
        pf[mi] = *(const bf16x8*)((char*)Pw + boff);
      }
#pragma unroll
      for (int ni = 0; ni < 4; ++ni) {
        const bf16x8 vf = *(const bf16x8*)(Vp + (size_t)(ni * 16 + ll) * L_ + kv0 + ks * 32 + 8 * lg);
#pragma unroll
        for (int mi = 0; mi < 2; ++mi)
          o[mi][ni] = __builtin_amdgcn_mfma_f32_16x16x32_bf16(pf[mi], vf, o[mi][ni], 0, 0, 0);
      }
    }
  }

  // ---- normalize + write Ob[b][l][h*64+d] bf16
  const int b = bh >> 4, h = bh & 15;
  unsigned short* Op = Ob + ((size_t)b * L_ + q0) * D_ + h * HD_;
#pragma unroll
  for (int mi = 0; mi < 2; ++mi) {
    const float invl = 1.0f / lrow[mi];
    float iq[4];
#pragma unroll
    for (int rg = 0; rg < 4; ++rg) iq[rg] = __shfl(invl, lg * 4 + rg);
#pragma unroll
    for (int rg = 0; rg < 4; ++rg) {
      const int row = mi * 16 + lg * 4 + rg;
#pragma unroll
      for (int ni = 0; ni < 4; ++ni)
        Op[(size_t)row * D_ + ni * 16 + ll] = f2bf(o[mi][ni][rg] * iq[rg]);
    }
  }
}

// ---------------------------------------------------------------------------
extern "C" void kernel_launch(void* const* d_in, const int* in_sizes, int n_in,
                              void* d_out, int out_size, void* d_ws, size_t ws_size,
                              hipStream_t stream) {
  const float* x    = (const float*)d_in[0];
  const float* Wqkv = (const float*)d_in[1];
  const float* bqkv = (const float*)d_in[2];
  const float* Wout = (const float*)d_in[3];
  const float* bout = (const float*)d_in[4];
  float* out = (float*)d_out;

  char* ws = (char*)d_ws;                       // 48 MiB used
  unsigned short* xb    = (unsigned short*)(ws);                    // 8 MiB
  unsigned short* WqkvT = (unsigned short*)(ws + (8ull  << 20));    // 6 MiB
  unsigned short* WoutT = (unsigned short*)(ws + (14ull << 20));    // 2 MiB
  unsigned short* Qb    = (unsigned short*)(ws + (16ull << 20));    // 8 MiB
  unsigned short* Kb    = (unsigned short*)(ws + (24ull << 20));    // 8 MiB
  unsigned short* Vt    = (unsigned short*)(ws + (32ull << 20));    // 8 MiB
  unsigned short* Ob    = (unsigned short*)(ws + (40ull << 20));    // 8 MiB

  cast_x<<<(BL_ * D_ / 8 + 255) / 256, 256, 0, stream>>>(x, (u16x8*)xb, BL_ * D_ / 8);
  transpose_cast<<<dim3(3 * D_ / 32, D_ / 32), dim3(32, 8), 0, stream>>>(Wqkv, WqkvT, D_, 3 * D_);
  transpose_cast<<<dim3(D_ / 32, D_ / 32), dim3(32, 8), 0, stream>>>(Wout, WoutT, D_, D_);

  gemm_bt<0><<<dim3(3 * D_ / 128, BL_ / 128), 256, 0, stream>>>(
      xb, WqkvT, bqkv, nullptr, Qb, Kb, Vt, BL_, 3 * D_, D_);

  attn_kernel<<<B_ * H_ * (L_ / 128), 256, 0, stream>>>(Qb, Kb, Vt, Ob);

  gemm_bt<1><<<dim3(D_ / 128, BL_ / 128), 256, 0, stream>>>(
      Ob, WoutT, bout, out, nullptr, nullptr, nullptr, BL_, D_, D_);
}

// Round 3
// 169.770 us; speedup vs baseline: 1.3407x; 1.2402x over previous
//
#include <hip/hip_runtime.h>
#include <stdint.h>
#include <stddef.h>

// ---------------------------------------------------------------------------
// Fused transformer attention block for MI355X (gfx950)
//   x[2,2048,1024] fp32 -> QKV proj(+RoPE fused) -> 16-head softmax attn -> out proj
// bf16 MFMA (16x16x32), fp32 accumulate.
// R3: attn K/V LDS staging (double-buffered, swizzled-source global_load_lds,
//     shared across 4 waves, T3-minimal prefetch pipeline), XCD swizzle (T1),
//     setprio (T5), RoPE table instead of epilogue sincosf.
// ---------------------------------------------------------------------------

typedef short          bf16x8 __attribute__((ext_vector_type(8)));
typedef float          f32x4  __attribute__((ext_vector_type(4)));
typedef unsigned short u16x4  __attribute__((ext_vector_type(4)));
typedef unsigned short u16x8  __attribute__((ext_vector_type(8)));

#define B_   2
#define L_   2048
#define D_   1024
#define H_   16
#define HD_  64
#define BL_  4096           // B_*L_
#define LOG2E 1.4426950408889634f
#define QSC  0.18033688011112042f   // 0.125 * LOG2E (scale+log2e folded into Q)

__device__ __forceinline__ unsigned short f2bf(float f) {   // RNE f32->bf16
  unsigned int u = __float_as_uint(f);
  u += 0x7FFFu + ((u >> 16) & 1u);
  return (unsigned short)(u >> 16);
}
__device__ __forceinline__ float bf2f(unsigned short h) {
  return __uint_as_float(((unsigned int)h) << 16);
}
__device__ __forceinline__ uint32_t cvtpk_bf16(float lo, float hi) {
  uint32_t r;
  asm("v_cvt_pk_bf16_f32 %0, %1, %2" : "=v"(r) : "v"(lo), "v"(hi));
  return r;
}

// async global->LDS, 16B per lane; LDS dest is wave-uniform base + lane*16
__device__ __forceinline__ void gload_lds16(const unsigned short* g, unsigned short* l) {
  __builtin_amdgcn_global_load_lds(
      (__attribute__((address_space(1))) void*)g,
      (__attribute__((address_space(3))) void*)l, 16, 0, 0);
}

// ---------------------------------------------------------------------------
// x (fp32) -> bf16, vectorized 8/thread
// ---------------------------------------------------------------------------
__global__ void __launch_bounds__(256)
cast_x(const float* __restrict__ src, u16x8* __restrict__ dst, int n8) {
  const int i = blockIdx.x * 256 + threadIdx.x;
  if (i >= n8) return;
  const float4 a = ((const float4*)src)[2 * i];
  const float4 b = ((const float4*)src)[2 * i + 1];
  u16x8 o;
  o[0] = f2bf(a.x); o[1] = f2bf(a.y); o[2] = f2bf(a.z); o[3] = f2bf(a.w);
  o[4] = f2bf(b.x); o[5] = f2bf(b.y); o[6] = f2bf(b.z); o[7] = f2bf(b.w);
  dst[i] = o;
}

// ---------------------------------------------------------------------------
// W[K][N] fp32 -> Wt[N][K] bf16 (LDS tile transpose, padded)
// ---------------------------------------------------------------------------
__global__ void __launch_bounds__(256)
transpose_cast(const float* __restrict__ src, unsigned short* __restrict__ dst,
               int K, int N) {
  __shared__ float tile[32][33];
  const int n0 = blockIdx.x * 32, k0 = blockIdx.y * 32;
  const int tx = threadIdx.x, ty = threadIdx.y;   // (32,8)
#pragma unroll
  for (int i = 0; i < 4; ++i)
    tile[ty * 4 + i][tx] = src[(size_t)(k0 + ty * 4 + i) * N + n0 + tx];
  __syncthreads();
#pragma unroll
  for (int i = 0; i < 4; ++i)
    dst[(size_t)(n0 + ty * 4 + i) * K + k0 + tx] = f2bf(tile[tx][ty * 4 + i]);
}

// ---------------------------------------------------------------------------
// RoPE cos/sin table: tbl[pos][j] = (cos, sin), pos in [0,2048), j in [0,32)
// ---------------------------------------------------------------------------
__global__ void __launch_bounds__(256)
rope_tables(float2* __restrict__ tbl) {
  const int i = blockIdx.x * 256 + threadIdx.x;   // 65536
  const int pos = i >> 5, j = i & 31;
  const float inv = exp2f(-(float)j * 0.4152410118609203f);   // log2(1e4)/32
  float s, c;
  sincosf((float)pos * inv, &s, &c);
  tbl[i] = make_float2(c, s);
}

// ---------------------------------------------------------------------------
// GEMM (m97 structure): C[M][N] = A[M][K](bf16) * Bt[N][K](bf16)^T + bias
// 128x128 tile, BK=32, 4 waves 2x2, each wave 64x64 = 4x4 16x16 frags.
// MODE 0: epilogue -> RoPE(Q,K) (table) scatter to Qb/Kb [bh][L][64],
//         V -> Vt [bh][64][L]. Q additionally scaled by 0.125*LOG2E.
// MODE 1: plain epilogue -> outF fp32 [M][N]
// ---------------------------------------------------------------------------
template <int MODE>
__global__ void __launch_bounds__(256)
gemm_bt(const unsigned short* __restrict__ A,
        const unsigned short* __restrict__ Bt,
        const float* __restrict__ bias,
        const float2* __restrict__ rt,
        float* __restrict__ outF,
        unsigned short* __restrict__ Qb,
        unsigned short* __restrict__ Kb,
        unsigned short* __restrict__ Vt,
        int M, int N, int K) {
  __shared__ unsigned short As[2][128 * 32];
  __shared__ unsigned short Bs[2][128 * 32];
  const int tid = threadIdx.x;
  const int w = tid >> 6, l = tid & 63;
  const int lg = l >> 4, ll = l & 15;
  const int m0 = blockIdx.y * 128, n0 = blockIdx.x * 128;
  const int wm = (w >> 1) * 64, wn = (w & 1) * 64;

  f32x4 acc[4][4] = {};

  const int srow = w * 16 + (l >> 2);     // + c*64
  const int scol = (l & 3) * 8;
  const unsigned short* gA = A  + (size_t)(m0 + srow) * K + scol;
  const unsigned short* gB = Bt + (size_t)(n0 + srow) * K + scol;
  const int ldsoff = (w * 1024) >> 1;     // ushort index, + c*2048

  const int NT = K >> 5;
  int buf = 0;

  auto stage = [&](int bsel, int kt) {
    const int kk = kt * 32;
#pragma unroll
    for (int c = 0; c < 2; ++c) {
      gload_lds16(gA + (size_t)c * 64 * K + kk, &As[bsel][ldsoff + c * 2048]);
      gload_lds16(gB + (size_t)c * 64 * K + kk, &Bs[bsel][ldsoff + c * 2048]);
    }
  };

  stage(0, 0);
  for (int kt = 0; kt < NT; ++kt) {
    __syncthreads();                      // drains vmcnt -> staged tile visible
    if (kt + 1 < NT) stage(buf ^ 1, kt + 1);
    const unsigned short* pa = &As[buf][0];
    const unsigned short* pb = &Bs[buf][0];
    bf16x8 af[4], bfv[4];
#pragma unroll
    for (int mi = 0; mi < 4; ++mi)
      af[mi] = *(const bf16x8*)(pa + (wm + mi * 16 + ll) * 32 + 8 * lg);
#pragma unroll
    for (int ni = 0; ni < 4; ++ni)
      bfv[ni] = *(const bf16x8*)(pb + (wn + ni * 16 + ll) * 32 + 8 * lg);
    __builtin_amdgcn_s_setprio(1);
#pragma unroll
    for (int mi = 0; mi < 4; ++mi)
#pragma unroll
      for (int ni = 0; ni < 4; ++ni)
        acc[mi][ni] = __builtin_amdgcn_mfma_f32_16x16x32_bf16(
            af[mi], bfv[ni], acc[mi][ni], 0, 0, 0);
    __builtin_amdgcn_s_setprio(0);
    buf ^= 1;
  }

  // epilogue. C layout: row = (l>>4)*4 + reg, col = l&15   (guide m89/m91)
  if (MODE == 0) {
    const int t = (n0 + wn) >> 10;        // 0=q 1=k 2=v, wave-uniform (64 | 1024)
    if (t == 2) {                         // V transposed: Vt[bh][d][pos..pos+3]
#pragma unroll
      for (int ni = 0; ni < 4; ++ni) {
        const int n = n0 + wn + ni * 16 + ll;
        const float bv = bias[n];
        const int r = n & 1023;
        const int h = r >> 6, d = r & 63;
#pragma unroll
        for (int mi = 0; mi < 4; ++mi) {
          const int row0 = m0 + wm + mi * 16 + lg * 4;
          const int b   = row0 >> 11;
          const int pos = row0 & 2047;
          const int bh  = b * H_ + h;
          u16x4 pk;
#pragma unroll
          for (int rg = 0; rg < 4; ++rg) pk[rg] = f2bf(acc[mi][ni][rg] + bv);
          *(u16x4*)(Vt + ((size_t)bh * HD_ + d) * L_ + pos) = pk;
        }
      }
    } else {                              // Q/K: fused RoPE via table, pairs (d, d+32)
      unsigned short* dst = (t == 0) ? Qb : Kb;
      const float qsc = (t == 0) ? QSC : 1.0f;
      const int h = ((n0 + wn) & 1023) >> 6;   // wave-uniform
#pragma unroll
      for (int ni = 0; ni < 2; ++ni) {
        const int d = ni * 16 + ll;       // 0..31
        const float bv1 = bias[n0 + wn + ni * 16 + ll];
        const float bv2 = bias[n0 + wn + (ni + 2) * 16 + ll];
#pragma unroll
        for (int mi = 0; mi < 4; ++mi) {
          const int row0 = m0 + wm + mi * 16 + lg * 4;
          const int b   = row0 >> 11;
          const int pos0 = row0 & 2047;
          unsigned short* base = dst + (size_t)(b * H_ + h) * L_ * HD_;
#pragma unroll
          for (int rg = 0; rg < 4; ++rg) {
            const int pos = pos0 + rg;
            const float2 cs = rt[pos * 32 + d];
            const float q1 = acc[mi][ni][rg] + bv1;
            const float q2 = acc[mi][ni + 2][rg] + bv2;
            base[(size_t)pos * HD_ + d]      = f2bf((q1 * cs.x - q2 * cs.y) * qsc);
            base[(size_t)pos * HD_ + d + 32] = f2bf((q2 * cs.x + q1 * cs.y) * qsc);
          }
        }
      }
    }
  } else {
#pragma unroll
    for (int ni = 0; ni < 4; ++ni) {
      const int n = n0 + wn + ni * 16 + ll;
      const float bv = bias[n];
#pragma unroll
      for (int mi = 0; mi < 4; ++mi) {
        const int row0 = m0 + wm + mi * 16 + lg * 4;
#pragma unroll
        for (int rg = 0; rg < 4; ++rg)
          outF[(size_t)(row0 + rg) * N + n] = acc[mi][ni][rg] + bv;
      }
    }
  }
}

// ---------------------------------------------------------------------------
// Flash attention (R3): block = 4 waves x 32 q-rows of one (b,h); KVBLK=64.
// K,V tiles staged in LDS (double-buffered, shared by all 4 waves) via
// global_load_lds with pre-swizzled global source (linear LDS dest + XOR on
// read -> conflict-free ds_read_b128). T3-minimal pipeline: issue STAGE(t+1),
// compute(t) from LDS, one __syncthreads per iter (drains vmcnt+lgkm).
// Swapped QK^T (S^T lane-local softmax), defer-max, cvt_pk, XCD swizzle.
// ---------------------------------------------------------------------------
__global__ void __launch_bounds__(256)
attn_kernel(const unsigned short* __restrict__ Qb,
            const unsigned short* __restrict__ Kb,
            const unsigned short* __restrict__ Vt,
            unsigned short* __restrict__ Ob) {
  __shared__ unsigned short Ks[2][4096];     // [kv 64][d 64] bf16, swizzled
  __shared__ unsigned short Vs[2][4096];     // [d 64][kv 64] bf16, swizzled
  __shared__ unsigned short Pl[4][2048];     // per-wave 32x64 bf16, swizzled
  const int tid = threadIdx.x, w = tid >> 6, l = tid & 63;
  const int lg = l >> 4, ll = l & 15;
  // T1: bijective XCD swizzle (512 blocks, 512 % 8 == 0)
  const int bid = ((blockIdx.x & 7) << 6) + (blockIdx.x >> 3);
  const int bh  = bid >> 4;                  // 16 blocks per (b,h)
  const int q0  = (bid & 15) * 128 + w * 32;
  const unsigned short* Qp = Qb + ((size_t)bh * L_ + q0) * HD_;
  const unsigned short* Kp = Kb + (size_t)bh * L_ * HD_;
  const unsigned short* Vp = Vt + (size_t)bh * HD_ * L_;
  unsigned short* Pw = &Pl[w][0];

  // staging geometry: thread tid writes tile row (c*32 + tid>>3), 16B slot
  // (tid&7); source column pre-swizzled so LDS[row][s] = G[row][s^(row&7)].
  const int srow = tid >> 3;                       // 0..31
  const int scol = ((tid & 7) ^ (srow & 7)) * 8;   // ushort col in [0,64)
  auto stage = [&](int bsel, int kv0) {
    unsigned short* kb = &Ks[bsel][w * 512];       // wave-uniform base
    unsigned short* vb = &Vs[bsel][w * 512];
#pragma unroll
    for (int c = 0; c < 2; ++c)
      gload_lds16(Kp + (size_t)(kv0 + c * 32 + srow) * HD_ + scol, kb + c * 2048);
#pragma unroll
    for (int c = 0; c < 2; ++c)
      gload_lds16(Vp + (size_t)(c * 32 + srow) * L_ + kv0 + scol, vb + c * 2048);
  };

  // hoist Q fragments (B-operand: col = l&15, k = 8*(l>>4)+j)
  bf16x8 qf[2][2];
#pragma unroll
  for (int mi = 0; mi < 2; ++mi)
#pragma unroll
    for (int ks = 0; ks < 2; ++ks)
      qf[mi][ks] = *(const bf16x8*)(Qp + (size_t)(mi * 16 + ll) * HD_ + ks * 32 + 8 * lg);

  f32x4 o[2][4] = {};
  float mrow[2] = {-1e30f, -1e30f};          // log2-domain running max (per q=ll)
  float lrow[2] = {0.f, 0.f};

  stage(0, 0);
  __syncthreads();

  int buf = 0;
  for (int t = 0; t < 32; ++t) {
    if (t + 1 < 32) stage(buf ^ 1, (t + 1) * 64);   // prefetch next tile
    const char* Ksb = (const char*)&Ks[buf][0];
    const char* Vsb = (const char*)&Vs[buf][0];

    // ---- S^T = K Q^T from LDS (scale*log2e folded into Q)
    bf16x8 kfr[4][2];
#pragma unroll
    for (int ni = 0; ni < 4; ++ni)
#pragma unroll
      for (int ks = 0; ks < 2; ++ks)
        kfr[ni][ks] = *(const bf16x8*)(Ksb + (ni * 16 + ll) * 128 +
                                       ((ks * 64 + lg * 16) ^ ((ll & 7) << 4)));
    f32x4 s[2][4] = {};
    __builtin_amdgcn_s_setprio(1);
#pragma unroll
    for (int ks = 0; ks < 2; ++ks)
#pragma unroll
      for (int ni = 0; ni < 4; ++ni)
#pragma unroll
        for (int mi = 0; mi < 2; ++mi)
          s[mi][ni] = __builtin_amdgcn_mfma_f32_16x16x32_bf16(kfr[ni][ks], qf[mi][ks], s[mi][ni], 0, 0, 0);
    __builtin_amdgcn_s_setprio(0);

    // ---- per-lane max over 16 in-register k-values, then 2 shuffles
    float mx[2];
#pragma unroll
    for (int mi = 0; mi < 2; ++mi) {
      float a0 = fmaxf(fmaxf(s[mi][0][0], s[mi][0][1]), fmaxf(s[mi][0][2], s[mi][0][3]));
      float a1 = fmaxf(fmaxf(s[mi][1][0], s[mi][1][1]), fmaxf(s[mi][1][2], s[mi][1][3]));
      float a2 = fmaxf(fmaxf(s[mi][2][0], s[mi][2][1]), fmaxf(s[mi][2][2], s[mi][2][3]));
      float a3 = fmaxf(fmaxf(s[mi][3][0], s[mi][3][1]), fmaxf(s[mi][3][2], s[mi][3][3]));
      float a  = fmaxf(fmaxf(a0, a1), fmaxf(a2, a3));
      a = fmaxf(a, __shfl_xor(a, 16));
      a = fmaxf(a, __shfl_xor(a, 32));
      mx[mi] = a;
    }
    // ---- defer-max: rescale only when max grew by >8 (log2 domain)
    const bool need = (mx[0] > mrow[0] + 8.f) || (mx[1] > mrow[1] + 8.f);
    if (__any(need)) {
#pragma unroll
      for (int mi = 0; mi < 2; ++mi) {
        const float mnew = fmaxf(mrow[mi], mx[mi]);
        const float f = exp2f(mrow[mi] - mnew);
        mrow[mi] = mnew;
        lrow[mi] *= f;
        float fq[4];
#pragma unroll
        for (int rg = 0; rg < 4; ++rg) fq[rg] = __shfl(f, lg * 4 + rg);
#pragma unroll
        for (int ni = 0; ni < 4; ++ni)
#pragma unroll
          for (int rg = 0; rg < 4; ++rg) o[mi][ni][rg] *= fq[rg];
      }
    }
    // ---- P = exp2(S - m), in-lane sum, pack bf16, b64 store to swizzled LDS
#pragma unroll
    for (int mi = 0; mi < 2; ++mi) {
      float rs = 0.f;
#pragma unroll
      for (int ni = 0; ni < 4; ++ni) {
        const float p0 = exp2f(s[mi][ni][0] - mrow[mi]);
        const float p1 = exp2f(s[mi][ni][1] - mrow[mi]);
        const float p2 = exp2f(s[mi][ni][2] - mrow[mi]);
        const float p3 = exp2f(s[mi][ni][3] - mrow[mi]);
        rs += (p0 + p1) + (p2 + p3);
        uint2 pk;
        pk.x = cvtpk_bf16(p0, p1);
        pk.y = cvtpk_bf16(p2, p3);
        const int boff = (mi * 2048 + ll * 128 + ni * 32 + lg * 8) ^ ((ll & 7) << 4);
        *(uint2*)((char*)Pw + boff) = pk;
      }
      rs += __shfl_xor(rs, 16);
      rs += __shfl_xor(rs, 32);
      lrow[mi] += rs;
    }
    asm volatile("s_waitcnt lgkmcnt(0)" ::: "memory");
    __builtin_amdgcn_sched_barrier(0);
    // ---- O += P V   (A = P from LDS, B = V from swizzled LDS)
#pragma unroll
    for (int ks = 0; ks < 2; ++ks) {
      bf16x8 pf[2], vf[4];
#pragma unroll
      for (int mi = 0; mi < 2; ++mi) {
        const int row = mi * 16 + ll;
        const int boff = (row * 128 + ks * 64 + lg * 16) ^ ((row & 7) << 4);
        pf[mi] = *(const bf16x8*)((char*)Pw + boff);
      }
#pragma unroll
      for (int ni = 0; ni < 4; ++ni)
        vf[ni] = *(const bf16x8*)(Vsb + (ni * 16 + ll) * 128 +
                                  ((ks * 64 + lg * 16) ^ ((ll & 7) << 4)));
      __builtin_amdgcn_s_setprio(1);
#pragma unroll
      for (int ni = 0; ni < 4; ++ni)
#pragma unroll
        for (int mi = 0; mi < 2; ++mi)
          o[mi][ni] = __builtin_amdgcn_mfma_f32_16x16x32_bf16(pf[mi], vf[ni], o[mi][ni], 0, 0, 0);
      __builtin_amdgcn_s_setprio(0);
    }
    __syncthreads();                       // staged(t+1) complete; buffers safe
    buf ^= 1;
  }

  // ---- normalize + write Ob[b][l][h*64+d] bf16
  const int b = bh >> 4, h = bh & 15;
  unsigned short* Op = Ob + ((size_t)b * L_ + q0) * D_ + h * HD_;
#pragma unroll
  for (int mi = 0; mi < 2; ++mi) {
    const float invl = 1.0f / lrow[mi];
    float iq[4];
#pragma unroll
    for (int rg = 0; rg < 4; ++rg) iq[rg] = __shfl(invl, lg * 4 + rg);
#pragma unroll
    for (int rg = 0; rg < 4; ++rg) {
      const int row = mi * 16 + lg * 4 + rg;
#pragma unroll
      for (int ni = 0; ni < 4; ++ni)
        Op[(size_t)row * D_ + ni * 16 + ll] = f2bf(o[mi][ni][rg] * iq[rg]);
    }
  }
}

// ---------------------------------------------------------------------------
extern "C" void kernel_launch(void* const* d_in, const int* in_sizes, int n_in,
                              void* d_out, int out_size, void* d_ws, size_t ws_size,
                              hipStream_t stream) {
  const float* x    = (const float*)d_in[0];
  const float* Wqkv = (const float*)d_in[1];
  const float* bqkv = (const float*)d_in[2];
  const float* Wout = (const float*)d_in[3];
  const float* bout = (const float*)d_in[4];
  float* out = (float*)d_out;

  char* ws = (char*)d_ws;                       // 48 MiB used
  unsigned short* xb    = (unsigned short*)(ws);                    // 8 MiB
  unsigned short* WqkvT = (unsigned short*)(ws + (8ull  << 20));    // 6 MiB
  unsigned short* WoutT = (unsigned short*)(ws + (14ull << 20));    // 2 MiB
  unsigned short* Qb    = (unsigned short*)(ws + (16ull << 20));    // 8 MiB
  unsigned short* Kb    = (unsigned short*)(ws + (24ull << 20));    // 8 MiB
  unsigned short* Vt    = (unsigned short*)(ws + (32ull << 20));    // 8 MiB
  unsigned short* Ob    = (unsigned short*)(ws + (40ull << 20));    // 8 MiB
  // RoPE table lives at the head of the Ob region: only needed during GEMM1,
  // which completes before attn overwrites Ob. 2048*32*8B = 512 KiB.
  float2* rtbl = (float2*)(ws + (40ull << 20));

  rope_tables<<<256, 256, 0, stream>>>(rtbl);
  cast_x<<<(BL_ * D_ / 8 + 255) / 256, 256, 0, stream>>>(x, (u16x8*)xb, BL_ * D_ / 8);
  transpose_cast<<<dim3(3 * D_ / 32, D_ / 32), dim3(32, 8), 0, stream>>>(Wqkv, WqkvT, D_, 3 * D_);
  transpose_cast<<<dim3(D_ / 32, D_ / 32), dim3(32, 8), 0, stream>>>(Wout, WoutT, D_, D_);

  gemm_bt<0><<<dim3(3 * D_ / 128, BL_ / 128), 256, 0, stream>>>(
      xb, WqkvT, bqkv, rtbl, nullptr, Qb, Kb, Vt, BL_, 3 * D_, D_);

  attn_kernel<<<B_ * H_ * (L_ / 128), 256, 0, stream>>>(Qb, Kb, Vt, Ob);

  gemm_bt<1><<<dim3(D_ / 128, BL_ / 128), 256, 0, stream>>>(
      Ob, WoutT, bout, nullptr, out, nullptr, nullptr, nullptr, BL_, D_, D_);
}